// Round 1
// baseline (14167.766 us; speedup 1.0000x reference)
//
#include <hip/hip_runtime.h>
#include <hip/hip_bf16.h>

#define NENT 40000
#define NREL 20
#define DIM 128
#define NBASIS 8

// W[r] = sum_b comp[r,b] * basis[b]  for both layers at once
__global__ void k_weights(const float* __restrict__ comp1, const float* __restrict__ basis1,
                          const float* __restrict__ comp2, const float* __restrict__ basis2,
                          float* __restrict__ W1, float* __restrict__ W2) {
    int idx = blockIdx.x * 256 + threadIdx.x;
    if (idx >= NREL * DIM * DIM) return;
    int r = idx >> 14;      // / (128*128)
    int io = idx & 16383;
    float s1 = 0.f, s2 = 0.f;
#pragma unroll
    for (int b = 0; b < NBASIS; ++b) {
        s1 += comp1[r * NBASIS + b] * basis1[b * 16384 + io];
        s2 += comp2[r * NBASIS + b] * basis2[b * 16384 + io];
    }
    W1[idx] = s1;
    W2[idx] = s2;
}

__global__ void k_hist_deg(const int* __restrict__ et, const int* __restrict__ dst, int E,
                           int* __restrict__ hist, float* __restrict__ deg) {
    __shared__ int lh[NREL];
    if (threadIdx.x < NREL) lh[threadIdx.x] = 0;
    __syncthreads();
    int e = blockIdx.x * blockDim.x + threadIdx.x;
    if (e < E) {
        atomicAdd(&lh[et[e]], 1);
        atomicAdd(&deg[dst[e]], 1.0f);
    }
    __syncthreads();
    if (threadIdx.x < NREL) atomicAdd(&hist[threadIdx.x], lh[threadIdx.x]);
}

// single-thread exclusive scan over 20 bins (trivial)
__global__ void k_scan(const int* __restrict__ hist, int* __restrict__ offs,
                       int* __restrict__ chunk_offs, int* __restrict__ cursor) {
    offs[0] = 0;
    chunk_offs[0] = 0;
    for (int r = 0; r < NREL; ++r) {
        offs[r + 1] = offs[r] + hist[r];
        chunk_offs[r + 1] = chunk_offs[r] + (hist[r] + 63) / 64;
        cursor[r] = offs[r];
    }
}

// counting-sort scatter: edge ids grouped by relation. Wave-aggregated atomics
// (20 ballots/wave) to avoid 640K serialized atomics on 20 counters.
__global__ void k_scatter(const int* __restrict__ et, int E, int* __restrict__ cursor,
                          int* __restrict__ sorted) {
    int e = blockIdx.x * blockDim.x + threadIdx.x;
    if (e >= E) return;
    int r = et[e];
    int lane = threadIdx.x & 63;
    unsigned long long lanebit = 1ull << lane;
    for (int j = 0; j < NREL; ++j) {
        unsigned long long m = __ballot(r == j);
        if (r == j) {
            int lead = __ffsll(m) - 1;
            int rank = __popcll(m & (lanebit - 1));
            int basep = 0;
            if (lane == lead) basep = atomicAdd(&cursor[j], __popcll(m));
            basep = __shfl(basep, lead);
            sorted[basep + rank] = e;
        }
    }
}

// Per-relation batched edge transform: for a chunk of 64 edges of relation r,
//   Y[64,128] = X[src rows][64,128] @ W_r[128,128],  atomically added into agg[dst].
// X tile staged in LDS (padded stride 132 -> only 2-way bank aliasing, free).
// W_r rows streamed from global (L2-resident, 4 distinct float4s per wave-load).
__global__ __launch_bounds__(256) void k_edge_gemm(
    const float* __restrict__ x, const float* __restrict__ W,
    const int* __restrict__ sorted, const int* __restrict__ offs,
    const int* __restrict__ chunk_offs,
    const int* __restrict__ src, const int* __restrict__ dstA,
    float* __restrict__ agg) {
    __shared__ __align__(16) float Xs[64][132];
    __shared__ int eDst[64];

    int b = blockIdx.x;
    if (b >= chunk_offs[NREL]) return;
    int r = 0;
    while (chunk_offs[r + 1] <= b) r++;
    int chunk = b - chunk_offs[r];
    int s0 = offs[r] + chunk * 64;
    int cnt = min(64, offs[r + 1] - s0);

    int t = threadIdx.x;
    // stage X rows: 8 passes, 8 rows/pass, 32 threads per row (one float4 each)
#pragma unroll
    for (int p = 0; p < 8; ++p) {
        int e = (t >> 5) + p * 8;
        int c4 = t & 31;
        float4 v = make_float4(0.f, 0.f, 0.f, 0.f);
        if (e < cnt) {
            int eid = sorted[s0 + e];
            int s = src[eid];
            v = *(const float4*)(x + s * DIM + c4 * 4);
            if (c4 == 0) eDst[e] = dstA[eid];
        }
        *(float4*)(&Xs[e][c4 * 4]) = v;
    }
    __syncthreads();

    int e = t >> 2;            // 0..63
    int ob = (t & 3) * 32;     // output column base
    float acc[32];
#pragma unroll
    for (int j = 0; j < 32; ++j) acc[j] = 0.f;

    const float4* Wr = (const float4*)(W + r * DIM * DIM);
    for (int i = 0; i < DIM; ++i) {
        float xi = Xs[e][i];
        const float4* wrow = Wr + i * (DIM / 4) + (ob >> 2);
#pragma unroll
        for (int j4 = 0; j4 < 8; ++j4) {
            float4 w = wrow[j4];
            acc[j4 * 4 + 0] += xi * w.x;
            acc[j4 * 4 + 1] += xi * w.y;
            acc[j4 * 4 + 2] += xi * w.z;
            acc[j4 * 4 + 3] += xi * w.w;
        }
    }

    if (e < cnt) {
        float* ap = agg + (long)eDst[e] * DIM + ob;
#pragma unroll
        for (int j = 0; j < 32; ++j) atomicAdd(ap + j, acc[j]);
    }
}

// out[n,o] = act( agg[n,o]/max(deg,1) + (x@root)[n,o] + bias[o] )
__global__ __launch_bounds__(256) void k_finish(
    const float* __restrict__ x, const float* __restrict__ agg,
    const float* __restrict__ deg, const float* __restrict__ root,
    const float* __restrict__ bias, float* __restrict__ out, int act) {
    int n = blockIdx.x * 2 + (threadIdx.x >> 7);
    int o = threadIdx.x & 127;
    if (n >= NENT) return;
    const float* xr = x + (long)n * DIM;
    float s = 0.f;
    for (int i = 0; i < DIM; ++i) s += xr[i] * root[i * DIM + o];
    float dg = deg[n];
    dg = dg < 1.f ? 1.f : dg;
    float v = agg[(long)n * DIM + o] / dg + s + bias[o];
    out[(long)n * DIM + o] = act ? tanhf(v) : v;
}

__global__ void k_rel(const float* __restrict__ rel, const float* __restrict__ wrel,
                      float* __restrict__ out, int nrows) {
    int idx = blockIdx.x * 256 + threadIdx.x;
    if (idx >= nrows * DIM) return;
    int j = idx >> 7, o = idx & 127;
    float s = 0.f;
    for (int i = 0; i < DIM; ++i) s += rel[j * DIM + i] * wrel[i * DIM + o];
    out[idx] = s;
}

extern "C" void kernel_launch(void* const* d_in, const int* in_sizes, int n_in,
                              void* d_out, int out_size, void* d_ws, size_t ws_size,
                              hipStream_t stream) {
    const int* edge_index = (const int*)d_in[0];
    const int* edge_type  = (const int*)d_in[1];
    const float* init_embed = (const float*)d_in[2];
    const float* init_rel   = (const float*)d_in[3];
    const float* w_rel      = (const float*)d_in[4];
    const float* comp1  = (const float*)d_in[5];
    const float* basis1 = (const float*)d_in[6];
    const float* root1  = (const float*)d_in[7];
    const float* bias1  = (const float*)d_in[8];
    const float* comp2  = (const float*)d_in[9];
    const float* basis2 = (const float*)d_in[10];
    const float* root2  = (const float*)d_in[11];
    const float* bias2  = (const float*)d_in[12];

    int E = in_sizes[1];
    const int* src = edge_index;
    const int* dst = edge_index + E;
    int relrows = in_sizes[3] / DIM;   // 40

    // workspace layout (all 16B-aligned at the float4-accessed regions)
    float* W1  = (float*)d_ws;
    float* W2  = W1 + NREL * DIM * DIM;
    float* agg = W2 + NREL * DIM * DIM;
    float* h   = agg + (long)NENT * DIM;
    float* deg = h + (long)NENT * DIM;
    int* hist       = (int*)(deg + NENT);
    int* offs       = hist + NREL;
    int* chunk_offs = offs + NREL + 1;
    int* cursor     = chunk_offs + NREL + 1;
    int* sorted     = cursor + NREL;

    float* outx = (float*)d_out;
    float* outr = outx + (long)NENT * DIM;

    hipMemsetAsync(hist, 0, NREL * sizeof(int), stream);
    hipMemsetAsync(deg, 0, NENT * sizeof(float), stream);

    k_weights<<<(NREL * DIM * DIM + 255) / 256, 256, 0, stream>>>(comp1, basis1, comp2, basis2, W1, W2);
    k_hist_deg<<<(E + 255) / 256, 256, 0, stream>>>(edge_type, dst, E, hist, deg);
    k_scan<<<1, 1, 0, stream>>>(hist, offs, chunk_offs, cursor);
    k_scatter<<<(E + 255) / 256, 256, 0, stream>>>(edge_type, E, cursor, sorted);

    int gx = (E + 63) / 64 + NREL;  // upper bound on total chunks

    // layer 1: x = tanh(agg/deg + x@root1 + bias1)
    hipMemsetAsync(agg, 0, (size_t)NENT * DIM * sizeof(float), stream);
    k_edge_gemm<<<gx, 256, 0, stream>>>(init_embed, W1, sorted, offs, chunk_offs, src, dst, agg);
    k_finish<<<NENT / 2, 256, 0, stream>>>(init_embed, agg, deg, root1, bias1, h, 1);

    // layer 2: out = agg/deg + h@root2 + bias2
    hipMemsetAsync(agg, 0, (size_t)NENT * DIM * sizeof(float), stream);
    k_edge_gemm<<<gx, 256, 0, stream>>>(h, W2, sorted, offs, chunk_offs, src, dst, agg);
    k_finish<<<NENT / 2, 256, 0, stream>>>(h, agg, deg, root2, bias2, outx, 0);

    // relation output: r = init_rel @ w_rel
    k_rel<<<(relrows * DIM + 255) / 256, 256, 0, stream>>>(init_rel, w_rel, outr, relrows);
}